// Round 7
// baseline (104.376 us; speedup 1.0000x reference)
//
#include <hip/hip_runtime.h>
#include <hip/hip_bf16.h>

// MXFP8Linear: out[n,j] = sum_b sx[n,b]*sw[j,b]*dot32(fp8(x),fp8(w)) + bias[j]
// Strategy: qdq both matrices to bf16 with scales folded in, then bf16 MFMA
// GEMM (A * B^T, both K-contig).
// R5: BM=128 BN=64, 4 waves, dbuf, counted vmcnt(6) + raw barriers.
// R7: 2D-chunked XCD swizzle — each XCD owns an 8x8 block of tiles so its
// concurrent panel working set (~6MB, 8x reuse) lives in its 4MB L2 instead
// of thrashing to Infinity Cache (theory: gemm is L3-BW-bound at ~400MB).

typedef __attribute__((ext_vector_type(8))) __bf16 bf16x8;
typedef __attribute__((ext_vector_type(4))) float f32x4;

#define NMAT 2048
#define FP8_MAX 448.0f

__device__ inline unsigned short bfbits(float f) {
  union { __hip_bfloat16 h; unsigned short u; } cv;
  cv.h = __float2bfloat16(f);
  return cv.u;
}

// quantize a,b to fp8 e4m3 (HW RNE, OCP on gfx950), dequant, pack 2 bf16
__device__ inline unsigned pack2(float a, float b, float scale) {
  int p = __builtin_amdgcn_cvt_pk_fp8_f32(a / scale, b / scale, 0, false);
  float qa = __builtin_amdgcn_cvt_f32_fp8(p, 0) * scale;
  float qb = __builtin_amdgcn_cvt_f32_fp8(p, 1) * scale;
  return (unsigned)bfbits(qa) | ((unsigned)bfbits(qb) << 16);
}

// Coalesced qdq: lane loads float4 coalesced; 32-block = 8 consecutive lanes;
// amax via shfl_xor(1,2,4); 8B/lane coalesced store. One launch for x and w.
__global__ __launch_bounds__(256) void qdq_kernel(const float* __restrict__ x,
                                                  uint2* __restrict__ xo,
                                                  const float* __restrict__ w,
                                                  uint2* __restrict__ wo) {
  int g = blockIdx.x;
  const float* in;
  uint2* out;
  if (g >= 4096) { in = w; out = wo; g -= 4096; }
  else           { in = x; out = xo; }
  const int t = threadIdx.x;
  const size_t base = (size_t)g * 1024;  // floats per workgroup
  float4 v = ((const float4*)(in + base))[t];
  float amax = fmaxf(fmaxf(fabsf(v.x), fabsf(v.y)), fmaxf(fabsf(v.z), fabsf(v.w)));
  amax = fmaxf(amax, __shfl_xor(amax, 1));
  amax = fmaxf(amax, __shfl_xor(amax, 2));
  amax = fmaxf(amax, __shfl_xor(amax, 4));
  float scale = fmaxf(amax / FP8_MAX, 1e-30f);  // real div to match reference
  uint2 r;
  r.x = pack2(v.x, v.y, scale);
  r.y = pack2(v.z, v.w, scale);
  out[base / 4 + t] = r;
}

// C[n,j] = sum_k A[n,k]*B[j,k] + bias[j]
// BM=128 BN=64 BK=64, 256 thr (4 waves 2Mx2N, wave tile 64x32), dbuf LDS 48KB.
// Tile map: XCD x (= bid&7 under round-robin dispatch) owns the 8x8 chunk of
// (128x64) tiles at (tr0,tc0) = ((x>>2)*8, (x&3)*8) — working set ~6MB in L2.
// Main loop per K-tile: STAGE(next) ; vmcnt(6) ; s_barrier ; compute(cur) ;
// s_barrier  — counted vmcnt keeps next tile's loads in flight (T4).
// LDS swizzle: LDS[r][c ^ ((r&7)<<4)] = G[r][c]; staging pre-swizzles the
// GLOBAL source (global_load_lds dest must stay linear), reads apply the XOR.
__global__ __launch_bounds__(256) void gemm_kernel(const __bf16* __restrict__ A,
                                                   const __bf16* __restrict__ B,
                                                   const float* __restrict__ bias,
                                                   float* __restrict__ C) {
  __shared__ __align__(16) char lds[49152];  // [buf][A 16K | B 8K]
  const int tid  = threadIdx.x;
  const int lane = tid & 63;
  const int wid  = tid >> 6;
  const int wr   = wid >> 1;   // 0..1 -> row offset wr*64
  const int wc   = wid & 1;    // 0..1 -> col offset wc*32

  // 2D-chunked XCD mapping: 512 tiles = (16 rows x 32 cols) of 128x64.
  const int bid = blockIdx.x;
  const int xcd = bid & 7;          // XCD under round-robin dispatch
  const int k8  = bid >> 3;         // 0..63: local tile within XCD chunk
  const int tr  = (xcd >> 2) * 8 + (k8 >> 3);  // 0..15
  const int tc  = (xcd & 3) * 8 + (k8 & 7);    // 0..31
  const int row0 = tr * 128;
  const int col0 = tc * 64;

  // ---- staging: A = 4 issues, B = 2 issues (256 thr x 16B = 4KB each) ----
  // issue i covers linear tile bytes [i*4096, (i+1)*4096); rows are 128B.
  int rS[4], cS[4];
#pragma unroll
  for (int i = 0; i < 4; ++i) {
    const int o = i * 4096 + tid * 16;
    rS[i] = o >> 7;
    cS[i] = (o & 127) ^ ((rS[i] & 7) << 4);  // pre-swizzled source col
  }
  const char* AgS[4];
  const char* BgS[2];
#pragma unroll
  for (int i = 0; i < 4; ++i)
    AgS[i] = (const char*)A + (size_t)(row0 + rS[i]) * 4096 + cS[i];
#pragma unroll
  for (int j = 0; j < 2; ++j)
    BgS[j] = (const char*)B + (size_t)(col0 + rS[j]) * 4096 + cS[j];
  const int dst = tid * 16;

#define STAGE(buf, kt) do {                                                      \
    const int kb = (kt) * 128;                                                   \
    char* lb = lds + (buf) * 24576;                                              \
    _Pragma("unroll")                                                            \
    for (int i = 0; i < 4; ++i)                                                  \
      __builtin_amdgcn_global_load_lds(                                          \
          (const __attribute__((address_space(1))) unsigned*)(AgS[i] + kb),      \
          (__attribute__((address_space(3))) unsigned*)(lb + i * 4096 + dst),    \
          16, 0, 0);                                                             \
    _Pragma("unroll")                                                            \
    for (int j = 0; j < 2; ++j)                                                  \
      __builtin_amdgcn_global_load_lds(                                          \
          (const __attribute__((address_space(1))) unsigned*)(BgS[j] + kb),      \
          (__attribute__((address_space(3))) unsigned*)(lb + 16384 + j * 4096 + dst), \
          16, 0, 0);                                                             \
  } while (0)

  // counted wait: tolerate the 6 loads just issued; everything older is done.
#define WAIT6_BAR() do {                                   \
    asm volatile("s_waitcnt vmcnt(6)" ::: "memory");       \
    __builtin_amdgcn_sched_barrier(0);                     \
    __builtin_amdgcn_s_barrier();                          \
  } while (0)
#define POST_BAR() do {                                    \
    __builtin_amdgcn_sched_barrier(0);                     \
    __builtin_amdgcn_s_barrier();                          \
  } while (0)

  // ---- fragment read addressing (swizzled) ----
  const int l15 = lane & 15;
  const int q16 = (lane >> 4) * 16;        // 16B sub-chunk within 32-k step
  const int swz = (l15 & 7) << 4;          // row&7 == l15&7 (row offsets %8==0)
  const int ck0 = q16 ^ swz;               // kk=0 byte col (swizzled)
  const int ck1 = (64 + q16) ^ swz;        // kk=1
  const int aRow = (wr * 64 + l15) * 128;  // byte row base for A frags
  const int bRow = (wc * 32 + l15) * 128;  // byte row base for B frags

  f32x4 acc[4][2] = {};

  auto compute = [&](const int buf) {
    const char* ab = lds + buf * 24576;
    const char* bb = ab + 16384;
    bf16x8 a0[4], a1[4], b0[2], b1[2];
#pragma unroll
    for (int m = 0; m < 4; ++m) {
      a0[m] = *(const bf16x8*)(ab + aRow + m * 2048 + ck0);
      a1[m] = *(const bf16x8*)(ab + aRow + m * 2048 + ck1);
    }
#pragma unroll
    for (int n = 0; n < 2; ++n) {
      b0[n] = *(const bf16x8*)(bb + bRow + n * 2048 + ck0);
      b1[n] = *(const bf16x8*)(bb + bRow + n * 2048 + ck1);
    }
#pragma unroll
    for (int m = 0; m < 4; ++m)
#pragma unroll
      for (int n = 0; n < 2; ++n) {
        acc[m][n] = __builtin_amdgcn_mfma_f32_16x16x32_bf16(a0[m], b0[n], acc[m][n], 0, 0, 0);
        acc[m][n] = __builtin_amdgcn_mfma_f32_16x16x32_bf16(a1[m], b1[n], acc[m][n], 0, 0, 0);
      }
  };

  STAGE(0, 0);
#pragma unroll 1
  for (int t = 0; t < 30; t += 2) {
    STAGE(1, t + 1);
    WAIT6_BAR();          // waits tile t's loads; t+1's stay in flight
    compute(0);
    POST_BAR();           // all waves done reading buf0 before next overwrite
    STAGE(0, t + 2);
    WAIT6_BAR();
    compute(1);
    POST_BAR();
  }
  STAGE(1, 31);
  WAIT6_BAR();
  compute(0);             // tile 30
  POST_BAR();
  asm volatile("s_waitcnt vmcnt(0)" ::: "memory");
  __builtin_amdgcn_sched_barrier(0);
  __builtin_amdgcn_s_barrier();
  compute(1);             // tile 31

  // epilogue: C/D layout col=lane&15, row=(lane>>4)*4+reg  [m89 verified]
  const int rb = row0 + wr * 64 + (lane >> 4) * 4;
#pragma unroll
  for (int n = 0; n < 2; ++n) {
    const int j = col0 + wc * 32 + n * 16 + l15;
    const float bv = bias[j];
#pragma unroll
    for (int m = 0; m < 4; ++m)
#pragma unroll
      for (int r = 0; r < 4; ++r)
        C[(size_t)(rb + m * 16 + r) * NMAT + j] = acc[m][n][r] + bv;
  }
#undef STAGE
#undef WAIT6_BAR
#undef POST_BAR
}

extern "C" void kernel_launch(void* const* d_in, const int* in_sizes, int n_in,
                              void* d_out, int out_size, void* d_ws, size_t ws_size,
                              hipStream_t stream) {
  const float* x  = (const float*)d_in[0];
  const float* w  = (const float*)d_in[1];
  const float* bs = (const float*)d_in[2];
  float* out = (float*)d_out;

  uint2* xd = (uint2*)d_ws;                       // 2048x2048 bf16 = 8MB
  uint2* wd = xd + (NMAT * (size_t)NMAT / 4);     // next 8MB

  qdq_kernel<<<dim3(8192), dim3(256), 0, stream>>>(x, xd, w, wd);

  gemm_kernel<<<dim3(512), dim3(256), 0, stream>>>((const __bf16*)xd,
                                                   (const __bf16*)wd, bs, out);
}